// Round 8
// baseline (220.723 us; speedup 1.0000x reference)
//
#include <hip/hip_runtime.h>
#include <hip/hip_bf16.h>
#include <stdint.h>

// MultiHeadAttention: B=2, P=2048, D_MODEL=1024, H=16, D=64, causal.
//
// R19: qkv_gemm256_k rewritten as BK=32, 4-LDS-buffer, depth-3 counted-vmcnt
// pipeline with ONE barrier per K-step (32 steps). R18's 4-phase gave each
// staged batch only a ~2-phase landing window and re-waited every phase
// (2190 cyc/phase vs ~500 real work). Now buffer s is issued at step s-3:
// window = 3 steps (~2400 cyc) >> 900-cyc HBM latency; vmcnt(8) keeps the
// 2 younger buffers in flight (T4: never drain to 0 mid-loop). ds_reads
// precede the DMA issues so a compiler-conservative drain costs at most the
// 1-step-old batch. BK=32 swizzle: stored chunk cl = cg ^ (r&3) ^ ((r>>2)&3)
// (2 lanes/bank-slot on reads, free class). attn (R16) / out_gemm (R15
// 128-core) unchanged for attribution.

typedef __bf16 bf16x8 __attribute__((ext_vector_type(8)));
typedef float f32x4 __attribute__((ext_vector_type(4)));
typedef float f32x16 __attribute__((ext_vector_type(16)));
typedef unsigned short u16;

__device__ __forceinline__ u16 f2bf(float f) {
  unsigned u = __float_as_uint(f);
  u += 0x7fffu + ((u >> 16) & 1u);
  return (u16)(u >> 16);
}

__device__ __forceinline__ uint32_t cvtpk(float lo, float hi) {
  uint32_t r;
  asm("v_cvt_pk_bf16_f32 %0, %1, %2" : "=v"(r) : "v"(lo), "v"(hi));
  return r;
}

__device__ __forceinline__ void pl32swap(uint32_t& a, uint32_t& b) {
  asm volatile("v_permlane32_swap_b32 %0, %1" : "+v"(a), "+v"(b));
}

// ---- X f32 -> bf16 (coalesced, 8 elems/thread) ----
__global__ __launch_bounds__(256) void xcvt_k(const float* __restrict__ in,
                                              u16* __restrict__ out) {
  int i = (blockIdx.x * 256 + threadIdx.x) * 8;
  float4 f0 = *reinterpret_cast<const float4*>(in + i);
  float4 f1 = *reinterpret_cast<const float4*>(in + i + 4);
  u16 tmp[8] = {f2bf(f0.x), f2bf(f0.y), f2bf(f0.z), f2bf(f0.w),
                f2bf(f1.x), f2bf(f1.y), f2bf(f1.z), f2bf(f1.w)};
  *reinterpret_cast<uint4*>(out + i) = *reinterpret_cast<uint4*>(tmp);
}

// ---- generic weight transpose+convert: in f32 [B][R][C] -> out bf16 [B][C][R] ----
__global__ __launch_bounds__(256) void transpose_cvt_k(const float* __restrict__ in,
                                                       u16* __restrict__ out,
                                                       int R, int C) {
  __shared__ u16 tile[64][80];
  int b = blockIdx.z;
  int r0 = blockIdx.x * 64, c0 = blockIdx.y * 64;
  const float* ip = in + (size_t)b * R * C;
  u16* op = out + (size_t)b * R * C;
  int t = threadIdx.x;
  int r = t >> 2, cb = (t & 3) * 16;
  const float4* src = reinterpret_cast<const float4*>(ip + (size_t)(r0 + r) * C + c0 + cb);
  u16 tmp[16];
#pragma unroll
  for (int v = 0; v < 4; v++) {
    float4 f = src[v];
    tmp[v * 4 + 0] = f2bf(f.x);
    tmp[v * 4 + 1] = f2bf(f.y);
    tmp[v * 4 + 2] = f2bf(f.z);
    tmp[v * 4 + 3] = f2bf(f.w);
  }
  *reinterpret_cast<uint4*>(&tile[r][cb]) = *reinterpret_cast<uint4*>(&tmp[0]);
  *reinterpret_cast<uint4*>(&tile[r][cb + 8]) = *reinterpret_cast<uint4*>(&tmp[8]);
  __syncthreads();
  int c = t >> 2, rb = (t & 3) * 16;
  uint4 outv[2];
  u16* tp = reinterpret_cast<u16*>(outv);
#pragma unroll
  for (int j = 0; j < 16; j++) tp[j] = tile[rb + j][c];
  uint4* dst = reinterpret_cast<uint4*>(op + (size_t)(c0 + c) * R + r0 + rb);
  dst[0] = outv[0];
  dst[1] = outv[1];
}

// ---- fused q/k/v weight transpose: z = 0..47 -> (sel = z>>4, head = z&15) ----
__global__ __launch_bounds__(256) void transpose_qkv_k(const float* __restrict__ Wq,
                                                       const float* __restrict__ Wk,
                                                       const float* __restrict__ Wv,
                                                       u16* __restrict__ outBase) {
  __shared__ u16 tile[64][80];
  int z = blockIdx.z;
  int sel = z >> 4, head = z & 15;
  const float* W = (sel == 0) ? Wq : (sel == 1 ? Wk : Wv);
  const float* ip = W + (size_t)head * 65536;           // [1024][64]
  u16* op = outBase + (size_t)sel * 1048576 + (size_t)head * 65536;  // [64][1024]
  int r0 = blockIdx.x * 64;                              // row block in R=1024
  int t = threadIdx.x;
  int r = t >> 2, cb = (t & 3) * 16;
  const float4* src = reinterpret_cast<const float4*>(ip + (size_t)(r0 + r) * 64 + cb);
  u16 tmp[16];
#pragma unroll
  for (int v = 0; v < 4; v++) {
    float4 f = src[v];
    tmp[v * 4 + 0] = f2bf(f.x);
    tmp[v * 4 + 1] = f2bf(f.y);
    tmp[v * 4 + 2] = f2bf(f.z);
    tmp[v * 4 + 3] = f2bf(f.w);
  }
  *reinterpret_cast<uint4*>(&tile[r][cb]) = *reinterpret_cast<uint4*>(&tmp[0]);
  *reinterpret_cast<uint4*>(&tile[r][cb + 8]) = *reinterpret_cast<uint4*>(&tmp[8]);
  __syncthreads();
  int c = t >> 2, rb = (t & 3) * 16;
  uint4 outv[2];
  u16* tp = reinterpret_cast<u16*>(outv);
#pragma unroll
  for (int j = 0; j < 16; j++) tp[j] = tile[rb + j][c];
  uint4* dst = reinterpret_cast<uint4*>(op + (size_t)c * 1024 + r0 + rb);
  dst[0] = outv[0];
  dst[1] = outv[1];
}

// ---- direct global->LDS DMA, 16B per lane (dest = wave-uniform base + lane*16) ----
__device__ __forceinline__ void gload16(const u16* g, u16* l) {
  __builtin_amdgcn_global_load_lds(
      (__attribute__((address_space(1))) void*)(g),
      (__attribute__((address_space(3))) void*)(l), 16, 0, 0);
}

// ====== 128x128 GEMM core (R15 structure): dbuf, single-barrier prefetch ======
// Swizzle (rule #21): 16B chunk p at row r holds global chunk p ^ (r&7);
// stage pre-swizzles the per-lane SOURCE col, reads XOR their chunk index.
__device__ __forceinline__ void gemm128_core(const u16* __restrict__ A,
                                             const u16* __restrict__ BT,
                                             int m0, int n0,
                                             f32x4 (&acc)[4][4]) {
  __shared__ __align__(16) u16 As[2][128][64];
  __shared__ __align__(16) u16 Bs[2][128][64];
  int t = threadIdx.x, l = t & 63;
  int w = t >> 6, wm = w & 1, wn = w >> 1;
  int l15 = l & 15, q4 = l >> 4;
  int r8 = l >> 3;
  int cs = ((l & 7) ^ r8) * 8;
  int swz = l15 & 7;
  int srow = w * 32 + r8;
  const u16* ga = A + (size_t)(m0 + srow) * 1024 + cs;
  const u16* gb = BT + (size_t)(n0 + srow) * 1024 + cs;
  f32x4 z4 = {0.f, 0.f, 0.f, 0.f};
#pragma unroll
  for (int mi = 0; mi < 4; mi++)
#pragma unroll
    for (int nt = 0; nt < 4; nt++) acc[mi][nt] = z4;

#pragma unroll
  for (int i = 0; i < 4; i++) {
    gload16(ga + (size_t)(i * 8) * 1024, &As[0][w * 32 + i * 8][0]);
    gload16(gb + (size_t)(i * 8) * 1024, &Bs[0][w * 32 + i * 8][0]);
  }
  __syncthreads();

  for (int step = 0; step < 16; step++) {
    int cur = step & 1;
    if (step < 15) {
      int k0 = (step + 1) * 64;
#pragma unroll
      for (int i = 0; i < 4; i++) {
        gload16(ga + (size_t)(i * 8) * 1024 + k0, &As[cur ^ 1][w * 32 + i * 8][0]);
        gload16(gb + (size_t)(i * 8) * 1024 + k0, &Bs[cur ^ 1][w * 32 + i * 8][0]);
      }
    }
#pragma unroll
    for (int kk = 0; kk < 2; kk++) {
      bf16x8 af[4], bfr[4];
#pragma unroll
      for (int mi = 0; mi < 4; mi++)
        af[mi] = *reinterpret_cast<const bf16x8*>(
            &As[cur][wm * 64 + mi * 16 + l15][((kk * 4 + q4) ^ swz) * 8]);
#pragma unroll
      for (int nt = 0; nt < 4; nt++)
        bfr[nt] = *reinterpret_cast<const bf16x8*>(
            &Bs[cur][wn * 64 + nt * 16 + l15][((kk * 4 + q4) ^ swz) * 8]);
#pragma unroll
      for (int mi = 0; mi < 4; mi++)
#pragma unroll
        for (int nt = 0; nt < 4; nt++)
          acc[mi][nt] = __builtin_amdgcn_mfma_f32_16x16x32_bf16(af[mi], bfr[nt], acc[mi][nt], 0, 0, 0);
    }
    __syncthreads();
  }
}

// ====== 256x256 QKV GEMM: BK=32, 4 buffers, depth-3, one barrier/step ======
// 512 threads = 8 waves (2M x 4N); per-wave output 128x64. LDS: As[4][256][32]
// + Bs[4][256][32] = 128KB dynamic. Buffer for step s is issued at step s-3
// (prologue covers s=0,1,2). Step s: vmcnt(8) [buffer s landed; s+1, s+2 = 8
// loads in flight] -> s_barrier -> 12 ds_reads -> issue buffer s+3 (4 gloads)
// -> 32 MFMA. Overwrite of buf (s+3)&3 is safe: it was last read at step s-1,
// whose reads completed (lgkm-enforced via MFMA use) before each wave passed
// this step's barrier; the DMA issues after the barrier.
// Swizzle: stored chunk cl = cg ^ (r&3) ^ ((r>>2)&3); staging pre-swizzles the
// per-lane source (cg = (l&3)^((l>>2)&3)^((l>>4)&3)); reads use q4 ^ key(l15).
__global__ __launch_bounds__(512, 1) void qkv_gemm256_k(const u16* __restrict__ A,
                                                        const u16* __restrict__ BT,
                                                        u16* __restrict__ Q,
                                                        u16* __restrict__ K,
                                                        u16* __restrict__ VT2) {
  extern __shared__ __align__(16) u16 sm[];
  u16* As = sm;                      // [4][256][32]
  u16* Bs = sm + 4 * 256 * 32;       // [4][256][32]
  const float QSCALE = 0.125f * 1.44269504088896340736f;  // (1/sqrt(64))*log2(e)
  int m0 = blockIdx.x * 256, n0 = blockIdx.y * 256;
  int t = threadIdx.x, l = t & 63, w = t >> 6;   // w 0..7
  int wm = w >> 2, wn = w & 3;
  int l15 = l & 15, q4 = l >> 4;
  int key = (l15 & 3) ^ ((l15 >> 2) & 3);        // read-side chunk XOR key
  int rl = l >> 2;                                // staging: lane's row-in-16
  int cg = (l & 3) ^ (rl & 3) ^ ((rl >> 2) & 3);  // staging source chunk
  size_t lsrc = (size_t)rl * 1024 + cg * 8;       // per-lane source addend
  const u16* gA = A + (size_t)m0 * 1024;
  const u16* gB = BT + (size_t)n0 * 1024;
  int arow0 = w * 32;                             // wave's staging rows

  f32x4 acc[8][4];
  f32x4 z4 = {0.f, 0.f, 0.f, 0.f};
#pragma unroll
  for (int mi = 0; mi < 8; mi++)
#pragma unroll
    for (int nt = 0; nt < 4; nt++) acc[mi][nt] = z4;

  auto stage = [&](int buf, int k0) {  // 4 gloads/wave: A rows arow0,+16; B same
    u16* ab = As + (size_t)buf * 8192;
    u16* bb = Bs + (size_t)buf * 8192;
    gload16(gA + (size_t)arow0 * 1024 + k0 + lsrc, ab + (size_t)arow0 * 32);
    gload16(gA + (size_t)(arow0 + 16) * 1024 + k0 + lsrc, ab + (size_t)(arow0 + 16) * 32);
    gload16(gB + (size_t)arow0 * 1024 + k0 + lsrc, bb + (size_t)arow0 * 32);
    gload16(gB + (size_t)(arow0 + 16) * 1024 + k0 + lsrc, bb + (size_t)(arow0 + 16) * 32);
  };

  // prologue: issue buffers for steps 0,1,2 (12 gloads/wave outstanding)
  stage(0, 0);
  stage(1, 32);
  stage(2, 64);

  for (int s = 0; s < 32; s++) {
    int buf = s & 3;
    // counted wait: buffer s landed; keep buffers s+1, s+2 (8 loads) in flight
    if (s < 30)
      asm volatile("s_waitcnt vmcnt(8)" ::: "memory");
    else if (s == 30)
      asm volatile("s_waitcnt vmcnt(4)" ::: "memory");
    else
      asm volatile("s_waitcnt vmcnt(0)" ::: "memory");
    __builtin_amdgcn_s_barrier();

    const u16* ab = As + (size_t)buf * 8192;
    const u16* bb = Bs + (size_t)buf * 8192;
    bf16x8 af[8], bfr[4];
#pragma unroll
    for (int mi = 0; mi < 8; mi++)
      af[mi] = *reinterpret_cast<const bf16x8*>(
          &ab[(size_t)(wm * 128 + mi * 16 + l15) * 32 + (size_t)((q4 ^ key) * 8)]);
#pragma unroll
    for (int nt = 0; nt < 4; nt++)
      bfr[nt] = *reinterpret_cast<const bf16x8*>(
          &bb[(size_t)(wn * 64 + nt * 16 + l15) * 32 + (size_t)((q4 ^ key) * 8)]);

    if (s + 3 < 32) stage((s + 3) & 3, (s + 3) * 32);  // refill after reads issued

    __builtin_amdgcn_s_setprio(1);
#pragma unroll
    for (int mi = 0; mi < 8; mi++)
#pragma unroll
      for (int nt = 0; nt < 4; nt++)
        acc[mi][nt] = __builtin_amdgcn_mfma_f32_16x16x32_bf16(af[mi], bfr[nt], acc[mi][nt], 0, 0, 0);
    __builtin_amdgcn_s_setprio(0);
  }

  // ---- epilogue: Q/K scaled bf16, V tile-blocked ----
#pragma unroll
  for (int mi = 0; mi < 8; mi++) {
#pragma unroll
    for (int nt = 0; nt < 4; nt++) {
#pragma unroll
      for (int r = 0; r < 4; r++) {
        int m = m0 + wm * 128 + mi * 16 + q4 * 4 + r;
        int n = n0 + wn * 64 + nt * 16 + l15;
        int wsel = n >> 10, h = (n >> 6) & 15, d = n & 63;
        int b = m >> 11, p = m & 2047;
        size_t bh = (size_t)(b * 16 + h);
        float v = acc[mi][nt][r];
        if (wsel == 0)
          Q[(bh * 2048 + p) * 64 + d] = f2bf(v * QSCALE);
        else if (wsel == 1)
          K[(bh * 2048 + p) * 64 + d] = f2bf(v);
        else
          VT2[((bh * 32 + (p >> 6)) * 64 + d) * 64 + (p & 63)] = f2bf(v);
      }
    }
  }
}

// OUT: A=Ab [4096][1024], BT=WoT [1024][1024], O f32; grid (32, 8).
__global__ __launch_bounds__(256) void out_gemm128_k(const u16* __restrict__ A,
                                                     const u16* __restrict__ BT,
                                                     float* __restrict__ O) {
  int m0 = blockIdx.x * 128, n0 = blockIdx.y * 128;
  f32x4 acc[4][4];
  gemm128_core(A, BT, m0, n0, acc);
  int t = threadIdx.x, l = t & 63;
  int w = t >> 6, wm = w & 1, wn = w >> 1;
  int l15 = l & 15, q4 = l >> 4;
#pragma unroll
  for (int mi = 0; mi < 4; mi++) {
#pragma unroll
    for (int nt = 0; nt < 4; nt++) {
#pragma unroll
      for (int r = 0; r < 4; r++) {
        int m = m0 + wm * 64 + mi * 16 + q4 * 4 + r;
        int n = n0 + wn * 64 + nt * 16 + l15;
        O[(size_t)m * 1024 + n] = acc[mi][nt][r];
      }
    }
  }
}

// ---- flash attention: 32x32 swapped-QK^T, in-register softmax (T12) ----
__global__ __launch_bounds__(256) void attn_k(const u16* __restrict__ Q,
                                              const u16* __restrict__ K,
                                              const u16* __restrict__ VT2,
                                              u16* __restrict__ A) {
  __shared__ __align__(16) u16 Ks[2][64][64];
  __shared__ __align__(16) u16 Vs[2][64][64];
  __shared__ float rsbuf[4][32];
  int pr = blockIdx.x, h = blockIdx.y, b = blockIdx.z;
  int qt = b ? (15 - pr) : pr;
  size_t bh = (size_t)(b * 16 + h);
  const u16* Qp = Q + bh * 2048 * 64;
  const u16* Kp = K + bh * 2048 * 64;
  const u16* Vt = VT2 + bh * 32 * 64 * 64;   // [kt][d(64)][pc(64)]
  int t = threadIdx.x, l = t & 63, w = t >> 6;
  int l31 = l & 31, hi = l >> 5;
  int r8 = l >> 3, cs = ((l & 7) ^ r8) * 8;
  int swz = l31 & 7;
  const float NEG = -1e30f;
  int nkt = 2 * qt + 2;
  const u16* kbase = Kp + (size_t)(w * 16 + r8) * 64 + cs;
  const u16* vbase = Vt + (size_t)(w * 16 + r8) * 64 + cs;
  int qrow = qt * 128 + w * 32 + l31;

  bf16x8 qb[4];
#pragma unroll
  for (int kc = 0; kc < 4; kc++)
    qb[kc] = *reinterpret_cast<const bf16x8*>(Qp + (size_t)qrow * 64 + kc * 16 + hi * 8);

  f32x16 accO[2];
#pragma unroll
  for (int dh = 0; dh < 2; dh++)
#pragma unroll
    for (int r = 0; r < 16; r++) accO[dh][r] = 0.f;
  float rs = 0.f;

#pragma unroll
  for (int j = 0; j < 2; j++) {
    gload16(kbase + (size_t)(j * 512), &Ks[0][w * 16 + j * 8][0]);
    gload16(vbase + (size_t)(j * 512), &Vs[0][w * 16 + j * 8][0]);
  }
  __syncthreads();

  for (int kt = 0; kt < nkt; kt++) {
    int cur = kt & 1;
    if (kt < nkt - 1) {
      size_t off = (size_t)(kt + 1) * 4096;
#pragma unroll
      for (int j = 0; j < 2; j++) {
        gload16(kbase + off + j * 512, &Ks[cur ^ 1][w * 16 + j * 8][0]);
        gload16(vbase + off + j * 512, &Vs[cur ^ 1][w * 16 + j * 8][0]);
      }
    }

    f32x16 st[2];
#pragma unroll
    for (int kvh = 0; kvh < 2; kvh++)
#pragma unroll
      for (int r = 0; r < 16; r++) st[kvh][r] = 0.f;
    __builtin_amdgcn_s_setprio(1);
#pragma unroll
    for (int kc = 0; kc < 4; kc++) {
      bf16x8 ka0 = *reinterpret_cast<const bf16x8*>(
          &Ks[cur][l31][((2 * kc + hi) ^ swz) * 8]);
      bf16x8 ka1 = *reinterpret_cast<const bf16x8*>(
          &Ks[cur][32 + l31][((2 * kc + hi) ^ swz) * 8]);
      st[0] = __builtin_amdgcn_mfma_f32_32x32x16_bf16(ka0, qb[kc], st[0], 0, 0, 0);
      st[1] = __builtin_amdgcn_mfma_f32_32x32x16_bf16(ka1, qb[kc], st[1], 0, 0, 0);
    }
    __builtin_amdgcn_s_setprio(0);

    if (kt >= 2 * qt) {
      int kvb = kt * 64;
#pragma unroll
      for (int kvh = 0; kvh < 2; kvh++)
#pragma unroll
        for (int r = 0; r < 16; r++) {
          int kv = kvb + kvh * 32 + (r & 3) + 8 * (r >> 2) + 4 * hi;
          if (kv > qrow) st[kvh][r] = NEG;
        }
    }

#pragma unroll
    for (int kvh = 0; kvh < 2; kvh++)
#pragma unroll
      for (int r = 0; r < 16; r++) {
        float p = exp2f(st[kvh][r]);
        st[kvh][r] = p;
        rs += p;
      }

    bf16x8 pa[4];
#pragma unroll
    for (int ks = 0; ks < 4; ks++) {
      const f32x16& pp = st[ks >> 1];
      const int s8 = (ks & 1) * 8;
      uint32_t x0 = cvtpk(pp[s8 + 0], pp[s8 + 1]);
      uint32_t x1 = cvtpk(pp[s8 + 2], pp[s8 + 3]);
      uint32_t y0 = cvtpk(pp[s8 + 4], pp[s8 + 5]);
      uint32_t y1 = cvtpk(pp[s8 + 6], pp[s8 + 7]);
      pl32swap(x0, y0);
      pl32swap(x1, y1);
      uint32_t wds[4] = {x0, x1, y0, y1};
      pa[ks] = *reinterpret_cast<const bf16x8*>(wds);
    }

    __builtin_amdgcn_s_setprio(1);
#pragma unroll
    for (int dh = 0; dh < 2; dh++)
#pragma unroll
      for (int ks = 0; ks < 4; ks++) {
        bf16x8 vb = *reinterpret_cast<const bf16x8*>(
            &Vs[cur][dh * 32 + l31][((2 * ks + hi) ^ swz) * 8]);
        accO[dh] = __builtin_amdgcn_mfma_f32_32x32x16_bf16(pa[ks], vb, accO[dh], 0, 0, 0);
      }
    __builtin_amdgcn_s_setprio(0);
    __syncthreads();
  }

  rs += __shfl_xor(rs, 32, 64);
  if (hi == 0) rsbuf[w][l31] = rs;
  __syncthreads();
#pragma unroll
  for (int r = 0; r < 16; r++) {
    int ql = (r & 3) + 8 * (r >> 2) + 4 * hi;
    float inv = 1.f / rsbuf[w][ql];
    int prow = qt * 128 + w * 32 + ql;
    size_t base = ((size_t)(b * 2048 + prow)) * 1024 + h * 64;
    A[base + l31] = f2bf(accO[0][r] * inv);
    A[base + 32 + l31] = f2bf(accO[1][r] * inv);
  }
}

extern "C" void kernel_launch(void* const* d_in, const int* in_sizes, int n_in,
                              void* d_out, int out_size, void* d_ws, size_t ws_size,
                              hipStream_t stream) {
  const float* X  = (const float*)d_in[0];  // residual_stream [2][2048][1024]
  const float* Wq = (const float*)d_in[1];  // weight_query [16][1024][64]
  const float* Wk = (const float*)d_in[2];  // weight_key   [16][1024][64]
  const float* Wv = (const float*)d_in[3];  // weight_value [16][1024][64]
  const float* Wo = (const float*)d_in[4];  // weight_out   [1024][1024]
  float* out = (float*)d_out;               // [2][2048][1024] f32

  u16* ws = (u16*)d_ws;
  u16* WqT = ws;                    // [16][64][1024] x3 contiguous
  u16* WoT = WqT + 3145728;         // [1024][1024]
  u16* Xb  = WoT + 1048576;         // [4096][1024] bf16 (dead after qkv)
  u16* Qb  = Xb + 4194304;          // [32][2048][64]
  u16* Kb  = Qb + 4194304;          // [32][2048][64]
  u16* VT2 = Kb + 4194304;          // [32][32][64][64] tile-blocked
  u16* Ab  = Xb;                    // aliases Xb; total 40 MB

  xcvt_k<<<dim3(2048), 256, 0, stream>>>(X, Xb);
  transpose_qkv_k<<<dim3(16, 1, 48), 256, 0, stream>>>(Wq, Wk, Wv, WqT);
  transpose_cvt_k<<<dim3(16, 16, 1), 256, 0, stream>>>(Wo, WoT, 1024, 1024);

  qkv_gemm256_k<<<dim3(16, 12), 512, 131072, stream>>>(Xb, WqT, Qb, Kb, VT2);
  attn_k<<<dim3(16, 16, 2), 256, 0, stream>>>(Qb, Kb, VT2, Ab);
  out_gemm128_k<<<dim3(32, 8), 256, 0, stream>>>(Ab, WoT, out);
}

// Round 9
// 200.554 us; speedup vs baseline: 1.1006x; 1.1006x over previous
//
#include <hip/hip_runtime.h>
#include <hip/hip_bf16.h>
#include <stdint.h>

// MultiHeadAttention: B=2, P=2048, D_MODEL=1024, H=16, D=64, causal.
//
// R20: qkv back to 128x128 tile but BK=32 with 32KB double-buffered LDS ->
// grid 768 = exactly 3 blocks/CU (12 waves/CU, m97's occupancy class).
// R14-R19 retro: all 256-tile variants ran 192 blocks on 256 CUs (64 CUs
// idle, 1 block/CU, no TLP) and all landed 58-66us regardless of schedule;
// m114 says cross-block wave overlap at ~3 blocks/CU is what absorbs the
// barrier drain. Schedule is the simple proven R15 prefetch (DMA next ->
// compute cur -> one __syncthreads). BK=32 swizzle derived by the 8-lane
// bank-coverage test: read chunk (q4+(l15>>1))&3, store g=((l&3)-(l>>3))&3
// on the pre-swizzled source (lanes 0-7 cover all 32 banks, enumerated).
// attn (R16) / out_gemm (R15 BK64 core) unchanged for attribution.

typedef __bf16 bf16x8 __attribute__((ext_vector_type(8)));
typedef float f32x4 __attribute__((ext_vector_type(4)));
typedef float f32x16 __attribute__((ext_vector_type(16)));
typedef unsigned short u16;

__device__ __forceinline__ u16 f2bf(float f) {
  unsigned u = __float_as_uint(f);
  u += 0x7fffu + ((u >> 16) & 1u);
  return (u16)(u >> 16);
}

__device__ __forceinline__ uint32_t cvtpk(float lo, float hi) {
  uint32_t r;
  asm("v_cvt_pk_bf16_f32 %0, %1, %2" : "=v"(r) : "v"(lo), "v"(hi));
  return r;
}

__device__ __forceinline__ void pl32swap(uint32_t& a, uint32_t& b) {
  asm volatile("v_permlane32_swap_b32 %0, %1" : "+v"(a), "+v"(b));
}

// ---- X f32 -> bf16 (coalesced, 8 elems/thread) ----
__global__ __launch_bounds__(256) void xcvt_k(const float* __restrict__ in,
                                              u16* __restrict__ out) {
  int i = (blockIdx.x * 256 + threadIdx.x) * 8;
  float4 f0 = *reinterpret_cast<const float4*>(in + i);
  float4 f1 = *reinterpret_cast<const float4*>(in + i + 4);
  u16 tmp[8] = {f2bf(f0.x), f2bf(f0.y), f2bf(f0.z), f2bf(f0.w),
                f2bf(f1.x), f2bf(f1.y), f2bf(f1.z), f2bf(f1.w)};
  *reinterpret_cast<uint4*>(out + i) = *reinterpret_cast<uint4*>(tmp);
}

// ---- generic weight transpose+convert: in f32 [B][R][C] -> out bf16 [B][C][R] ----
__global__ __launch_bounds__(256) void transpose_cvt_k(const float* __restrict__ in,
                                                       u16* __restrict__ out,
                                                       int R, int C) {
  __shared__ u16 tile[64][80];
  int b = blockIdx.z;
  int r0 = blockIdx.x * 64, c0 = blockIdx.y * 64;
  const float* ip = in + (size_t)b * R * C;
  u16* op = out + (size_t)b * R * C;
  int t = threadIdx.x;
  int r = t >> 2, cb = (t & 3) * 16;
  const float4* src = reinterpret_cast<const float4*>(ip + (size_t)(r0 + r) * C + c0 + cb);
  u16 tmp[16];
#pragma unroll
  for (int v = 0; v < 4; v++) {
    float4 f = src[v];
    tmp[v * 4 + 0] = f2bf(f.x);
    tmp[v * 4 + 1] = f2bf(f.y);
    tmp[v * 4 + 2] = f2bf(f.z);
    tmp[v * 4 + 3] = f2bf(f.w);
  }
  *reinterpret_cast<uint4*>(&tile[r][cb]) = *reinterpret_cast<uint4*>(&tmp[0]);
  *reinterpret_cast<uint4*>(&tile[r][cb + 8]) = *reinterpret_cast<uint4*>(&tmp[8]);
  __syncthreads();
  int c = t >> 2, rb = (t & 3) * 16;
  uint4 outv[2];
  u16* tp = reinterpret_cast<u16*>(outv);
#pragma unroll
  for (int j = 0; j < 16; j++) tp[j] = tile[rb + j][c];
  uint4* dst = reinterpret_cast<uint4*>(op + (size_t)(c0 + c) * R + r0 + rb);
  dst[0] = outv[0];
  dst[1] = outv[1];
}

// ---- fused q/k/v weight transpose: z = 0..47 -> (sel = z>>4, head = z&15) ----
__global__ __launch_bounds__(256) void transpose_qkv_k(const float* __restrict__ Wq,
                                                       const float* __restrict__ Wk,
                                                       const float* __restrict__ Wv,
                                                       u16* __restrict__ outBase) {
  __shared__ u16 tile[64][80];
  int z = blockIdx.z;
  int sel = z >> 4, head = z & 15;
  const float* W = (sel == 0) ? Wq : (sel == 1 ? Wk : Wv);
  const float* ip = W + (size_t)head * 65536;           // [1024][64]
  u16* op = outBase + (size_t)sel * 1048576 + (size_t)head * 65536;  // [64][1024]
  int r0 = blockIdx.x * 64;                              // row block in R=1024
  int t = threadIdx.x;
  int r = t >> 2, cb = (t & 3) * 16;
  const float4* src = reinterpret_cast<const float4*>(ip + (size_t)(r0 + r) * 64 + cb);
  u16 tmp[16];
#pragma unroll
  for (int v = 0; v < 4; v++) {
    float4 f = src[v];
    tmp[v * 4 + 0] = f2bf(f.x);
    tmp[v * 4 + 1] = f2bf(f.y);
    tmp[v * 4 + 2] = f2bf(f.z);
    tmp[v * 4 + 3] = f2bf(f.w);
  }
  *reinterpret_cast<uint4*>(&tile[r][cb]) = *reinterpret_cast<uint4*>(&tmp[0]);
  *reinterpret_cast<uint4*>(&tile[r][cb + 8]) = *reinterpret_cast<uint4*>(&tmp[8]);
  __syncthreads();
  int c = t >> 2, rb = (t & 3) * 16;
  uint4 outv[2];
  u16* tp = reinterpret_cast<u16*>(outv);
#pragma unroll
  for (int j = 0; j < 16; j++) tp[j] = tile[rb + j][c];
  uint4* dst = reinterpret_cast<uint4*>(op + (size_t)c * 1024 + r0 + rb);
  dst[0] = outv[0];
  dst[1] = outv[1];
}

// ---- direct global->LDS DMA, 16B per lane (dest = wave-uniform base + lane*16) ----
__device__ __forceinline__ void gload16(const u16* g, u16* l) {
  __builtin_amdgcn_global_load_lds(
      (__attribute__((address_space(1))) void*)(g),
      (__attribute__((address_space(3))) void*)(l), 16, 0, 0);
}

// ====== 128x128 GEMM core (R15 structure, BK=64): used by out_gemm ======
__device__ __forceinline__ void gemm128_core(const u16* __restrict__ A,
                                             const u16* __restrict__ BT,
                                             int m0, int n0,
                                             f32x4 (&acc)[4][4]) {
  __shared__ __align__(16) u16 As[2][128][64];
  __shared__ __align__(16) u16 Bs[2][128][64];
  int t = threadIdx.x, l = t & 63;
  int w = t >> 6, wm = w & 1, wn = w >> 1;
  int l15 = l & 15, q4 = l >> 4;
  int r8 = l >> 3;
  int cs = ((l & 7) ^ r8) * 8;
  int swz = l15 & 7;
  int srow = w * 32 + r8;
  const u16* ga = A + (size_t)(m0 + srow) * 1024 + cs;
  const u16* gb = BT + (size_t)(n0 + srow) * 1024 + cs;
  f32x4 z4 = {0.f, 0.f, 0.f, 0.f};
#pragma unroll
  for (int mi = 0; mi < 4; mi++)
#pragma unroll
    for (int nt = 0; nt < 4; nt++) acc[mi][nt] = z4;

#pragma unroll
  for (int i = 0; i < 4; i++) {
    gload16(ga + (size_t)(i * 8) * 1024, &As[0][w * 32 + i * 8][0]);
    gload16(gb + (size_t)(i * 8) * 1024, &Bs[0][w * 32 + i * 8][0]);
  }
  __syncthreads();

  for (int step = 0; step < 16; step++) {
    int cur = step & 1;
    if (step < 15) {
      int k0 = (step + 1) * 64;
#pragma unroll
      for (int i = 0; i < 4; i++) {
        gload16(ga + (size_t)(i * 8) * 1024 + k0, &As[cur ^ 1][w * 32 + i * 8][0]);
        gload16(gb + (size_t)(i * 8) * 1024 + k0, &Bs[cur ^ 1][w * 32 + i * 8][0]);
      }
    }
#pragma unroll
    for (int kk = 0; kk < 2; kk++) {
      bf16x8 af[4], bfr[4];
#pragma unroll
      for (int mi = 0; mi < 4; mi++)
        af[mi] = *reinterpret_cast<const bf16x8*>(
            &As[cur][wm * 64 + mi * 16 + l15][((kk * 4 + q4) ^ swz) * 8]);
#pragma unroll
      for (int nt = 0; nt < 4; nt++)
        bfr[nt] = *reinterpret_cast<const bf16x8*>(
            &Bs[cur][wn * 64 + nt * 16 + l15][((kk * 4 + q4) ^ swz) * 8]);
#pragma unroll
      for (int mi = 0; mi < 4; mi++)
#pragma unroll
        for (int nt = 0; nt < 4; nt++)
          acc[mi][nt] = __builtin_amdgcn_mfma_f32_16x16x32_bf16(af[mi], bfr[nt], acc[mi][nt], 0, 0, 0);
    }
    __syncthreads();
  }
}

// ====== QKV GEMM: 128x128, BK=32, 32KB dbuf LDS -> 3 blocks/CU (768 blocks) ======
// Per step: issue 4 DMAs for step+1 into buf^1 -> 8 ds_read_b128 -> 16 MFMA
// -> one __syncthreads. The barrier's vmcnt drain overlaps with the other
// two co-resident blocks' compute (m114 implicit TLP).
// BK=32 swizzle (rows = 64B = 16 banks; 2 rows span 32 banks):
//   read chunk ch = (q4 + (l15>>1)) & 3  -> each 8 consecutive lanes cover
//   all 32 banks (enumerated); store: lane l of a 16-row gload writes local
//   chunk l&3 of row l>>2, so source takes global chunk g = ((l&3)-(l>>3))&3.
__global__ __launch_bounds__(256) void qkv_gemm128_k(const u16* __restrict__ A,
                                                     const u16* __restrict__ BT,
                                                     u16* __restrict__ Q,
                                                     u16* __restrict__ K,
                                                     u16* __restrict__ VT2) {
  __shared__ __align__(16) u16 As[2][128][32];
  __shared__ __align__(16) u16 Bs[2][128][32];
  const float QSCALE = 0.125f * 1.44269504088896340736f;  // (1/sqrt(64))*log2(e)
  int m0 = blockIdx.x * 128, n0 = blockIdx.y * 128;
  int t = threadIdx.x, l = t & 63;
  int w = t >> 6, wm = w & 1, wn = w >> 1;
  int l15 = l & 15, q4 = l >> 4;
  // staging source pre-swizzle: lane l -> row l>>2 (of a 16-row gload),
  // global chunk g = ((l&3) - (l>>3)) & 3
  int g = ((l & 3) - (l >> 3)) & 3;
  size_t lsrc = (size_t)(l >> 2) * 1024 + (size_t)(g * 8);
  const u16* ga = A + (size_t)(m0 + w * 32) * 1024 + lsrc;
  const u16* gb = BT + (size_t)(n0 + w * 32) * 1024 + lsrc;
  int rch = ((q4 + (l15 >> 1)) & 3) * 8;   // read-side chunk (u16 units)

  f32x4 acc[4][4];
  f32x4 z4 = {0.f, 0.f, 0.f, 0.f};
#pragma unroll
  for (int mi = 0; mi < 4; mi++)
#pragma unroll
    for (int nt = 0; nt < 4; nt++) acc[mi][nt] = z4;

  auto stage = [&](int buf, int k0) {  // 4 gloads/wave: A rows w*32,+16; B same
    gload16(ga + k0, &As[buf][w * 32][0]);
    gload16(ga + (size_t)16 * 1024 + k0, &As[buf][w * 32 + 16][0]);
    gload16(gb + k0, &Bs[buf][w * 32][0]);
    gload16(gb + (size_t)16 * 1024 + k0, &Bs[buf][w * 32 + 16][0]);
  };

  stage(0, 0);
  __syncthreads();

  for (int step = 0; step < 32; step++) {
    int cur = step & 1;
    if (step < 31) stage(cur ^ 1, (step + 1) * 32);  // prefetch next K-step
    bf16x8 af[4], bfr[4];
#pragma unroll
    for (int mi = 0; mi < 4; mi++)
      af[mi] = *reinterpret_cast<const bf16x8*>(&As[cur][wm * 64 + mi * 16 + l15][rch]);
#pragma unroll
    for (int nt = 0; nt < 4; nt++)
      bfr[nt] = *reinterpret_cast<const bf16x8*>(&Bs[cur][wn * 64 + nt * 16 + l15][rch]);
    __builtin_amdgcn_s_setprio(1);
#pragma unroll
    for (int mi = 0; mi < 4; mi++)
#pragma unroll
      for (int nt = 0; nt < 4; nt++)
        acc[mi][nt] = __builtin_amdgcn_mfma_f32_16x16x32_bf16(af[mi], bfr[nt], acc[mi][nt], 0, 0, 0);
    __builtin_amdgcn_s_setprio(0);
    __syncthreads();  // reads of cur done + prefetch DMA landed
  }

  // ---- epilogue: Q/K scaled bf16, V tile-blocked ----
#pragma unroll
  for (int mi = 0; mi < 4; mi++) {
#pragma unroll
    for (int nt = 0; nt < 4; nt++) {
#pragma unroll
      for (int r = 0; r < 4; r++) {
        int m = m0 + wm * 64 + mi * 16 + q4 * 4 + r;
        int n = n0 + wn * 64 + nt * 16 + l15;
        int wsel = n >> 10, h = (n >> 6) & 15, d = n & 63;
        int b = m >> 11, p = m & 2047;
        size_t bh = (size_t)(b * 16 + h);
        float v = acc[mi][nt][r];
        if (wsel == 0)
          Q[(bh * 2048 + p) * 64 + d] = f2bf(v * QSCALE);
        else if (wsel == 1)
          K[(bh * 2048 + p) * 64 + d] = f2bf(v);
        else
          VT2[((bh * 32 + (p >> 6)) * 64 + d) * 64 + (p & 63)] = f2bf(v);
      }
    }
  }
}

// OUT: A=Ab [4096][1024], BT=WoT [1024][1024], O f32; grid (32, 8).
__global__ __launch_bounds__(256) void out_gemm128_k(const u16* __restrict__ A,
                                                     const u16* __restrict__ BT,
                                                     float* __restrict__ O) {
  int m0 = blockIdx.x * 128, n0 = blockIdx.y * 128;
  f32x4 acc[4][4];
  gemm128_core(A, BT, m0, n0, acc);
  int t = threadIdx.x, l = t & 63;
  int w = t >> 6, wm = w & 1, wn = w >> 1;
  int l15 = l & 15, q4 = l >> 4;
#pragma unroll
  for (int mi = 0; mi < 4; mi++) {
#pragma unroll
    for (int nt = 0; nt < 4; nt++) {
#pragma unroll
      for (int r = 0; r < 4; r++) {
        int m = m0 + wm * 64 + mi * 16 + q4 * 4 + r;
        int n = n0 + wn * 64 + nt * 16 + l15;
        O[(size_t)m * 1024 + n] = acc[mi][nt][r];
      }
    }
  }
}

// ---- flash attention: 32x32 swapped-QK^T, in-register softmax (T12) ----
__global__ __launch_bounds__(256) void attn_k(const u16* __restrict__ Q,
                                              const u16* __restrict__ K,
                                              const u16* __restrict__ VT2,
                                              u16* __restrict__ A) {
  __shared__ __align__(16) u16 Ks[2][64][64];
  __shared__ __align__(16) u16 Vs[2][64][64];
  __shared__ float rsbuf[4][32];
  int pr = blockIdx.x, h = blockIdx.y, b = blockIdx.z;
  int qt = b ? (15 - pr) : pr;
  size_t bh = (size_t)(b * 16 + h);
  const u16* Qp = Q + bh * 2048 * 64;
  const u16* Kp = K + bh * 2048 * 64;
  const u16* Vt = VT2 + bh * 32 * 64 * 64;   // [kt][d(64)][pc(64)]
  int t = threadIdx.x, l = t & 63, w = t >> 6;
  int l31 = l & 31, hi = l >> 5;
  int r8 = l >> 3, cs = ((l & 7) ^ r8) * 8;
  int swz = l31 & 7;
  const float NEG = -1e30f;
  int nkt = 2 * qt + 2;
  const u16* kbase = Kp + (size_t)(w * 16 + r8) * 64 + cs;
  const u16* vbase = Vt + (size_t)(w * 16 + r8) * 64 + cs;
  int qrow = qt * 128 + w * 32 + l31;

  bf16x8 qb[4];
#pragma unroll
  for (int kc = 0; kc < 4; kc++)
    qb[kc] = *reinterpret_cast<const bf16x8*>(Qp + (size_t)qrow * 64 + kc * 16 + hi * 8);

  f32x16 accO[2];
#pragma unroll
  for (int dh = 0; dh < 2; dh++)
#pragma unroll
    for (int r = 0; r < 16; r++) accO[dh][r] = 0.f;
  float rs = 0.f;

#pragma unroll
  for (int j = 0; j < 2; j++) {
    gload16(kbase + (size_t)(j * 512), &Ks[0][w * 16 + j * 8][0]);
    gload16(vbase + (size_t)(j * 512), &Vs[0][w * 16 + j * 8][0]);
  }
  __syncthreads();

  for (int kt = 0; kt < nkt; kt++) {
    int cur = kt & 1;
    if (kt < nkt - 1) {
      size_t off = (size_t)(kt + 1) * 4096;
#pragma unroll
      for (int j = 0; j < 2; j++) {
        gload16(kbase + off + j * 512, &Ks[cur ^ 1][w * 16 + j * 8][0]);
        gload16(vbase + off + j * 512, &Vs[cur ^ 1][w * 16 + j * 8][0]);
      }
    }

    f32x16 st[2];
#pragma unroll
    for (int kvh = 0; kvh < 2; kvh++)
#pragma unroll
      for (int r = 0; r < 16; r++) st[kvh][r] = 0.f;
    __builtin_amdgcn_s_setprio(1);
#pragma unroll
    for (int kc = 0; kc < 4; kc++) {
      bf16x8 ka0 = *reinterpret_cast<const bf16x8*>(
          &Ks[cur][l31][((2 * kc + hi) ^ swz) * 8]);
      bf16x8 ka1 = *reinterpret_cast<const bf16x8*>(
          &Ks[cur][32 + l31][((2 * kc + hi) ^ swz) * 8]);
      st[0] = __builtin_amdgcn_mfma_f32_32x32x16_bf16(ka0, qb[kc], st[0], 0, 0, 0);
      st[1] = __builtin_amdgcn_mfma_f32_32x32x16_bf16(ka1, qb[kc], st[1], 0, 0, 0);
    }
    __builtin_amdgcn_s_setprio(0);

    if (kt >= 2 * qt) {
      int kvb = kt * 64;
#pragma unroll
      for (int kvh = 0; kvh < 2; kvh++)
#pragma unroll
        for (int r = 0; r < 16; r++) {
          int kv = kvb + kvh * 32 + (r & 3) + 8 * (r >> 2) + 4 * hi;
          if (kv > qrow) st[kvh][r] = NEG;
        }
    }

#pragma unroll
    for (int kvh = 0; kvh < 2; kvh++)
#pragma unroll
      for (int r = 0; r < 16; r++) {
        float p = exp2f(st[kvh][r]);
        st[kvh][r] = p;
        rs += p;
      }

    bf16x8 pa[4];
#pragma unroll
    for (int ks = 0; ks < 4; ks++) {
      const f32x16& pp = st[ks >> 1];
      const int s8 = (ks & 1) * 8;
      uint32_t x0 = cvtpk(pp[s8 + 0], pp[s8 + 1]);
      uint32_t x1 = cvtpk(pp[s8 + 2], pp[s8 + 3]);
      uint32_t y0 = cvtpk(pp[s8 + 4], pp[s8 + 5]);
      uint32_t y1 = cvtpk(pp[s8 + 6], pp[s8 + 7]);
      pl32swap(x0, y0);
      pl32swap(x1, y1);
      uint32_t wds[4] = {x0, x1, y0, y1};
      pa[ks] = *reinterpret_cast<const bf16x8*>(wds);
    }

    __builtin_amdgcn_s_setprio(1);
#pragma unroll
    for (int dh = 0; dh < 2; dh++)
#pragma unroll
      for (int ks = 0; ks < 4; ks++) {
        bf16x8 vb = *reinterpret_cast<const bf16x8*>(
            &Vs[cur][dh * 32 + l31][((2 * ks + hi) ^ swz) * 8]);
        accO[dh] = __builtin_amdgcn_mfma_f32_32x32x16_bf16(pa[ks], vb, accO[dh], 0, 0, 0);
      }
    __builtin_amdgcn_s_setprio(0);
    __syncthreads();
  }

  rs += __shfl_xor(rs, 32, 64);
  if (hi == 0) rsbuf[w][l31] = rs;
  __syncthreads();
#pragma unroll
  for (int r = 0; r < 16; r++) {
    int ql = (r & 3) + 8 * (r >> 2) + 4 * hi;
    float inv = 1.f / rsbuf[w][ql];
    int prow = qt * 128 + w * 32 + ql;
    size_t base = ((size_t)(b * 2048 + prow)) * 1024 + h * 64;
    A[base + l31] = f2bf(accO[0][r] * inv);
    A[base + 32 + l31] = f2bf(accO[1][r] * inv);
  }
}

extern "C" void kernel_launch(void* const* d_in, const int* in_sizes, int n_in,
                              void* d_out, int out_size, void* d_ws, size_t ws_size,
                              hipStream_t stream) {
  const float* X  = (const float*)d_in[0];  // residual_stream [2][2048][1024]
  const float* Wq = (const float*)d_in[1];  // weight_query [16][1024][64]
  const float* Wk = (const float*)d_in[2];  // weight_key   [16][1024][64]
  const float* Wv = (const float*)d_in[3];  // weight_value [16][1024][64]
  const float* Wo = (const float*)d_in[4];  // weight_out   [1024][1024]
  float* out = (float*)d_out;               // [2][2048][1024] f32

  u16* ws = (u16*)d_ws;
  u16* WqT = ws;                    // [16][64][1024] x3 contiguous
  u16* WoT = WqT + 3145728;         // [1024][1024]
  u16* Xb  = WoT + 1048576;         // [4096][1024] bf16 (dead after qkv)
  u16* Qb  = Xb + 4194304;          // [32][2048][64]
  u16* Kb  = Qb + 4194304;          // [32][2048][64]
  u16* VT2 = Kb + 4194304;          // [32][32][64][64] tile-blocked
  u16* Ab  = Xb;                    // aliases Xb; total 40 MB

  xcvt_k<<<dim3(2048), 256, 0, stream>>>(X, Xb);
  transpose_qkv_k<<<dim3(16, 1, 48), 256, 0, stream>>>(Wq, Wk, Wv, WqT);
  transpose_cvt_k<<<dim3(16, 16, 1), 256, 0, stream>>>(Wo, WoT, 1024, 1024);

  qkv_gemm128_k<<<dim3(32, 24), 256, 0, stream>>>(Xb, WqT, Qb, Kb, VT2);
  attn_k<<<dim3(16, 16, 2), 256, 0, stream>>>(Qb, Kb, VT2, Ab);
  out_gemm128_k<<<dim3(32, 8), 256, 0, stream>>>(Ab, WoT, out);
}

// Round 10
// 197.096 us; speedup vs baseline: 1.1199x; 1.0175x over previous
//
#include <hip/hip_runtime.h>
#include <hip/hip_bf16.h>
#include <stdint.h>

// MultiHeadAttention: B=2, P=2048, D_MODEL=1024, H=16, D=64, causal.
//
// R21: (a) prep fused: xcvt + transpose_qkv + transpose_cvt -> one prep_k
// (6 launches -> 4; kernel-sum ~150us vs dur 200us implies ~8us/launch gap).
// (b) attn_k: row-sum via MFMA ones-trick — rs_acc = mfma(pa[ks], ones)
// accumulated per iter (4 MFMAs on the idle matrix pipe) replaces the
// serial 32-add VALU chain AND the epilogue shfl+rsbuf+barrier: MFMA C
// layout puts rs_acc[r] in the same lane/row slot as accO[.][r], so
// inv = 1/rs_acc[r] directly. (c) qkv (R20 BK32 3-blk/CU) and out_gemm
// (R15 core) unchanged.

typedef __bf16 bf16x8 __attribute__((ext_vector_type(8)));
typedef float f32x4 __attribute__((ext_vector_type(4)));
typedef float f32x16 __attribute__((ext_vector_type(16)));
typedef unsigned short u16;

__device__ __forceinline__ u16 f2bf(float f) {
  unsigned u = __float_as_uint(f);
  u += 0x7fffu + ((u >> 16) & 1u);
  return (u16)(u >> 16);
}

__device__ __forceinline__ uint32_t cvtpk(float lo, float hi) {
  uint32_t r;
  asm("v_cvt_pk_bf16_f32 %0, %1, %2" : "=v"(r) : "v"(lo), "v"(hi));
  return r;
}

__device__ __forceinline__ void pl32swap(uint32_t& a, uint32_t& b) {
  asm volatile("v_permlane32_swap_b32 %0, %1" : "+v"(a), "+v"(b));
}

// ---- direct global->LDS DMA, 16B per lane (dest = wave-uniform base + lane*16) ----
__device__ __forceinline__ void gload16(const u16* g, u16* l) {
  __builtin_amdgcn_global_load_lds(
      (__attribute__((address_space(1))) void*)(g),
      (__attribute__((address_space(3))) void*)(l), 16, 0, 0);
}

// ====== fused prep: blocks [0,2048) xcvt; [2048,2816) qkv W transpose;
// ====== [2816,3072) Wo transpose. All paths 256 threads, block-uniform. ======
__global__ __launch_bounds__(256) void prep_k(const float* __restrict__ X,
                                              const float* __restrict__ Wq,
                                              const float* __restrict__ Wk,
                                              const float* __restrict__ Wv,
                                              const float* __restrict__ Wo,
                                              u16* __restrict__ Xb,
                                              u16* __restrict__ WqT,
                                              u16* __restrict__ WoT) {
  __shared__ u16 tile[64][80];
  int bid = blockIdx.x, t = threadIdx.x;

  if (bid < 2048) {  // ---- X f32 -> bf16, 8 elems/thread ----
    int i = (bid * 256 + t) * 8;
    float4 f0 = *reinterpret_cast<const float4*>(X + i);
    float4 f1 = *reinterpret_cast<const float4*>(X + i + 4);
    u16 tmp[8] = {f2bf(f0.x), f2bf(f0.y), f2bf(f0.z), f2bf(f0.w),
                  f2bf(f1.x), f2bf(f1.y), f2bf(f1.z), f2bf(f1.w)};
    *reinterpret_cast<uint4*>(Xb + i) = *reinterpret_cast<uint4*>(tmp);
    return;
  }

  const float* ip;
  u16* op;
  int r0, C, R;
  if (bid < 2816) {  // ---- q/k/v weight transpose: [1024][64] -> [64][1024] ----
    int tq = bid - 2048;           // 0..767
    int rb = tq & 15, z = tq >> 4; // z 0..47
    int sel = z >> 4, head = z & 15;
    const float* W = (sel == 0) ? Wq : (sel == 1 ? Wk : Wv);
    ip = W + (size_t)head * 65536;
    op = WqT + (size_t)sel * 1048576 + (size_t)head * 65536;
    r0 = rb * 64;
    C = 64;
    R = 1024;
    // fallthrough to shared transpose body with c0 = 0
    int r = t >> 2, cb = (t & 3) * 16;
    const float4* src = reinterpret_cast<const float4*>(ip + (size_t)(r0 + r) * C + cb);
    u16 tmp[16];
#pragma unroll
    for (int v = 0; v < 4; v++) {
      float4 f = src[v];
      tmp[v * 4 + 0] = f2bf(f.x);
      tmp[v * 4 + 1] = f2bf(f.y);
      tmp[v * 4 + 2] = f2bf(f.z);
      tmp[v * 4 + 3] = f2bf(f.w);
    }
    *reinterpret_cast<uint4*>(&tile[r][cb]) = *reinterpret_cast<uint4*>(&tmp[0]);
    *reinterpret_cast<uint4*>(&tile[r][cb + 8]) = *reinterpret_cast<uint4*>(&tmp[8]);
    __syncthreads();
    int c = t >> 2, rbq = (t & 3) * 16;
    uint4 outv[2];
    u16* tp = reinterpret_cast<u16*>(outv);
#pragma unroll
    for (int j = 0; j < 16; j++) tp[j] = tile[rbq + j][c];
    uint4* dst = reinterpret_cast<uint4*>(op + (size_t)c * R + r0 + rbq);
    dst[0] = outv[0];
    dst[1] = outv[1];
    return;
  }

  {  // ---- Wo transpose: [1024][1024] -> [1024][1024]^T ----
    int tc = bid - 2816;           // 0..255
    r0 = (tc & 15) * 64;
    int c0 = (tc >> 4) * 64;
    C = 1024; R = 1024;
    ip = Wo;
    op = WoT;
    int r = t >> 2, cb = (t & 3) * 16;
    const float4* src = reinterpret_cast<const float4*>(ip + (size_t)(r0 + r) * C + c0 + cb);
    u16 tmp[16];
#pragma unroll
    for (int v = 0; v < 4; v++) {
      float4 f = src[v];
      tmp[v * 4 + 0] = f2bf(f.x);
      tmp[v * 4 + 1] = f2bf(f.y);
      tmp[v * 4 + 2] = f2bf(f.z);
      tmp[v * 4 + 3] = f2bf(f.w);
    }
    *reinterpret_cast<uint4*>(&tile[r][cb]) = *reinterpret_cast<uint4*>(&tmp[0]);
    *reinterpret_cast<uint4*>(&tile[r][cb + 8]) = *reinterpret_cast<uint4*>(&tmp[8]);
    __syncthreads();
    int c = t >> 2, rbq = (t & 3) * 16;
    uint4 outv[2];
    u16* tp = reinterpret_cast<u16*>(outv);
#pragma unroll
    for (int j = 0; j < 16; j++) tp[j] = tile[rbq + j][c];
    uint4* dst = reinterpret_cast<uint4*>(op + (size_t)(c0 + c) * R + r0 + rbq);
    dst[0] = outv[0];
    dst[1] = outv[1];
  }
}

// ====== 128x128 GEMM core (R15 structure, BK=64): used by out_gemm ======
__device__ __forceinline__ void gemm128_core(const u16* __restrict__ A,
                                             const u16* __restrict__ BT,
                                             int m0, int n0,
                                             f32x4 (&acc)[4][4]) {
  __shared__ __align__(16) u16 As[2][128][64];
  __shared__ __align__(16) u16 Bs[2][128][64];
  int t = threadIdx.x, l = t & 63;
  int w = t >> 6, wm = w & 1, wn = w >> 1;
  int l15 = l & 15, q4 = l >> 4;
  int r8 = l >> 3;
  int cs = ((l & 7) ^ r8) * 8;
  int swz = l15 & 7;
  int srow = w * 32 + r8;
  const u16* ga = A + (size_t)(m0 + srow) * 1024 + cs;
  const u16* gb = BT + (size_t)(n0 + srow) * 1024 + cs;
  f32x4 z4 = {0.f, 0.f, 0.f, 0.f};
#pragma unroll
  for (int mi = 0; mi < 4; mi++)
#pragma unroll
    for (int nt = 0; nt < 4; nt++) acc[mi][nt] = z4;

#pragma unroll
  for (int i = 0; i < 4; i++) {
    gload16(ga + (size_t)(i * 8) * 1024, &As[0][w * 32 + i * 8][0]);
    gload16(gb + (size_t)(i * 8) * 1024, &Bs[0][w * 32 + i * 8][0]);
  }
  __syncthreads();

  for (int step = 0; step < 16; step++) {
    int cur = step & 1;
    if (step < 15) {
      int k0 = (step + 1) * 64;
#pragma unroll
      for (int i = 0; i < 4; i++) {
        gload16(ga + (size_t)(i * 8) * 1024 + k0, &As[cur ^ 1][w * 32 + i * 8][0]);
        gload16(gb + (size_t)(i * 8) * 1024 + k0, &Bs[cur ^ 1][w * 32 + i * 8][0]);
      }
    }
#pragma unroll
    for (int kk = 0; kk < 2; kk++) {
      bf16x8 af[4], bfr[4];
#pragma unroll
      for (int mi = 0; mi < 4; mi++)
        af[mi] = *reinterpret_cast<const bf16x8*>(
            &As[cur][wm * 64 + mi * 16 + l15][((kk * 4 + q4) ^ swz) * 8]);
#pragma unroll
      for (int nt = 0; nt < 4; nt++)
        bfr[nt] = *reinterpret_cast<const bf16x8*>(
            &Bs[cur][wn * 64 + nt * 16 + l15][((kk * 4 + q4) ^ swz) * 8]);
#pragma unroll
      for (int mi = 0; mi < 4; mi++)
#pragma unroll
        for (int nt = 0; nt < 4; nt++)
          acc[mi][nt] = __builtin_amdgcn_mfma_f32_16x16x32_bf16(af[mi], bfr[nt], acc[mi][nt], 0, 0, 0);
    }
    __syncthreads();
  }
}

// ====== QKV GEMM: 128x128, BK=32, 32KB dbuf LDS -> 3 blocks/CU (768 blocks) ======
__global__ __launch_bounds__(256) void qkv_gemm128_k(const u16* __restrict__ A,
                                                     const u16* __restrict__ BT,
                                                     u16* __restrict__ Q,
                                                     u16* __restrict__ K,
                                                     u16* __restrict__ VT2) {
  __shared__ __align__(16) u16 As[2][128][32];
  __shared__ __align__(16) u16 Bs[2][128][32];
  const float QSCALE = 0.125f * 1.44269504088896340736f;  // (1/sqrt(64))*log2(e)
  int m0 = blockIdx.x * 128, n0 = blockIdx.y * 128;
  int t = threadIdx.x, l = t & 63;
  int w = t >> 6, wm = w & 1, wn = w >> 1;
  int l15 = l & 15, q4 = l >> 4;
  int g = ((l & 3) - (l >> 3)) & 3;
  size_t lsrc = (size_t)(l >> 2) * 1024 + (size_t)(g * 8);
  const u16* ga = A + (size_t)(m0 + w * 32) * 1024 + lsrc;
  const u16* gb = BT + (size_t)(n0 + w * 32) * 1024 + lsrc;
  int rch = ((q4 + (l15 >> 1)) & 3) * 8;

  f32x4 acc[4][4];
  f32x4 z4 = {0.f, 0.f, 0.f, 0.f};
#pragma unroll
  for (int mi = 0; mi < 4; mi++)
#pragma unroll
    for (int nt = 0; nt < 4; nt++) acc[mi][nt] = z4;

  auto stage = [&](int buf, int k0) {
    gload16(ga + k0, &As[buf][w * 32][0]);
    gload16(ga + (size_t)16 * 1024 + k0, &As[buf][w * 32 + 16][0]);
    gload16(gb + k0, &Bs[buf][w * 32][0]);
    gload16(gb + (size_t)16 * 1024 + k0, &Bs[buf][w * 32 + 16][0]);
  };

  stage(0, 0);
  __syncthreads();

  for (int step = 0; step < 32; step++) {
    int cur = step & 1;
    if (step < 31) stage(cur ^ 1, (step + 1) * 32);
    bf16x8 af[4], bfr[4];
#pragma unroll
    for (int mi = 0; mi < 4; mi++)
      af[mi] = *reinterpret_cast<const bf16x8*>(&As[cur][wm * 64 + mi * 16 + l15][rch]);
#pragma unroll
    for (int nt = 0; nt < 4; nt++)
      bfr[nt] = *reinterpret_cast<const bf16x8*>(&Bs[cur][wn * 64 + nt * 16 + l15][rch]);
    __builtin_amdgcn_s_setprio(1);
#pragma unroll
    for (int mi = 0; mi < 4; mi++)
#pragma unroll
      for (int nt = 0; nt < 4; nt++)
        acc[mi][nt] = __builtin_amdgcn_mfma_f32_16x16x32_bf16(af[mi], bfr[nt], acc[mi][nt], 0, 0, 0);
    __builtin_amdgcn_s_setprio(0);
    __syncthreads();
  }

#pragma unroll
  for (int mi = 0; mi < 4; mi++) {
#pragma unroll
    for (int nt = 0; nt < 4; nt++) {
#pragma unroll
      for (int r = 0; r < 4; r++) {
        int m = m0 + wm * 64 + mi * 16 + q4 * 4 + r;
        int n = n0 + wn * 64 + nt * 16 + l15;
        int wsel = n >> 10, h = (n >> 6) & 15, d = n & 63;
        int b = m >> 11, p = m & 2047;
        size_t bh = (size_t)(b * 16 + h);
        float v = acc[mi][nt][r];
        if (wsel == 0)
          Q[(bh * 2048 + p) * 64 + d] = f2bf(v * QSCALE);
        else if (wsel == 1)
          K[(bh * 2048 + p) * 64 + d] = f2bf(v);
        else
          VT2[((bh * 32 + (p >> 6)) * 64 + d) * 64 + (p & 63)] = f2bf(v);
      }
    }
  }
}

// OUT: A=Ab [4096][1024], BT=WoT [1024][1024], O f32; grid (32, 8).
__global__ __launch_bounds__(256) void out_gemm128_k(const u16* __restrict__ A,
                                                     const u16* __restrict__ BT,
                                                     float* __restrict__ O) {
  int m0 = blockIdx.x * 128, n0 = blockIdx.y * 128;
  f32x4 acc[4][4];
  gemm128_core(A, BT, m0, n0, acc);
  int t = threadIdx.x, l = t & 63;
  int w = t >> 6, wm = w & 1, wn = w >> 1;
  int l15 = l & 15, q4 = l >> 4;
#pragma unroll
  for (int mi = 0; mi < 4; mi++) {
#pragma unroll
    for (int nt = 0; nt < 4; nt++) {
#pragma unroll
      for (int r = 0; r < 4; r++) {
        int m = m0 + wm * 64 + mi * 16 + q4 * 4 + r;
        int n = n0 + wn * 64 + nt * 16 + l15;
        O[(size_t)m * 1024 + n] = acc[mi][nt][r];
      }
    }
  }
}

// ---- flash attention: 32x32 swapped-QK^T, in-register softmax (T12) ----
// R21: row-sum via MFMA ones-trick; rs_acc[r] lands in the same lane/row
// slot as accO[.][r] -> epilogue needs no shuffle/LDS broadcast.
__global__ __launch_bounds__(256) void attn_k(const u16* __restrict__ Q,
                                              const u16* __restrict__ K,
                                              const u16* __restrict__ VT2,
                                              u16* __restrict__ A) {
  __shared__ __align__(16) u16 Ks[2][64][64];
  __shared__ __align__(16) u16 Vs[2][64][64];
  int pr = blockIdx.x, h = blockIdx.y, b = blockIdx.z;
  int qt = b ? (15 - pr) : pr;
  size_t bh = (size_t)(b * 16 + h);
  const u16* Qp = Q + bh * 2048 * 64;
  const u16* Kp = K + bh * 2048 * 64;
  const u16* Vt = VT2 + bh * 32 * 64 * 64;   // [kt][d(64)][pc(64)]
  int t = threadIdx.x, l = t & 63, w = t >> 6;
  int l31 = l & 31, hi = l >> 5;
  int r8 = l >> 3, cs = ((l & 7) ^ r8) * 8;
  int swz = l31 & 7;
  const float NEG = -1e30f;
  int nkt = 2 * qt + 2;
  const u16* kbase = Kp + (size_t)(w * 16 + r8) * 64 + cs;
  const u16* vbase = Vt + (size_t)(w * 16 + r8) * 64 + cs;
  int qrow = qt * 128 + w * 32 + l31;

  // ones B-operand for the row-sum MFMA (bf16 1.0 = 0x3F80)
  uint32_t onesw[4] = {0x3F803F80u, 0x3F803F80u, 0x3F803F80u, 0x3F803F80u};
  bf16x8 onesb = *reinterpret_cast<const bf16x8*>(onesw);

  bf16x8 qb[4];
#pragma unroll
  for (int kc = 0; kc < 4; kc++)
    qb[kc] = *reinterpret_cast<const bf16x8*>(Qp + (size_t)qrow * 64 + kc * 16 + hi * 8);

  f32x16 accO[2], rs_acc;
#pragma unroll
  for (int dh = 0; dh < 2; dh++)
#pragma unroll
    for (int r = 0; r < 16; r++) accO[dh][r] = 0.f;
#pragma unroll
  for (int r = 0; r < 16; r++) rs_acc[r] = 0.f;

#pragma unroll
  for (int j = 0; j < 2; j++) {
    gload16(kbase + (size_t)(j * 512), &Ks[0][w * 16 + j * 8][0]);
    gload16(vbase + (size_t)(j * 512), &Vs[0][w * 16 + j * 8][0]);
  }
  __syncthreads();

  for (int kt = 0; kt < nkt; kt++) {
    int cur = kt & 1;
    if (kt < nkt - 1) {
      size_t off = (size_t)(kt + 1) * 4096;
#pragma unroll
      for (int j = 0; j < 2; j++) {
        gload16(kbase + off + j * 512, &Ks[cur ^ 1][w * 16 + j * 8][0]);
        gload16(vbase + off + j * 512, &Vs[cur ^ 1][w * 16 + j * 8][0]);
      }
    }

    f32x16 st[2];
#pragma unroll
    for (int kvh = 0; kvh < 2; kvh++)
#pragma unroll
      for (int r = 0; r < 16; r++) st[kvh][r] = 0.f;
    __builtin_amdgcn_s_setprio(1);
#pragma unroll
    for (int kc = 0; kc < 4; kc++) {
      bf16x8 ka0 = *reinterpret_cast<const bf16x8*>(
          &Ks[cur][l31][((2 * kc + hi) ^ swz) * 8]);
      bf16x8 ka1 = *reinterpret_cast<const bf16x8*>(
          &Ks[cur][32 + l31][((2 * kc + hi) ^ swz) * 8]);
      st[0] = __builtin_amdgcn_mfma_f32_32x32x16_bf16(ka0, qb[kc], st[0], 0, 0, 0);
      st[1] = __builtin_amdgcn_mfma_f32_32x32x16_bf16(ka1, qb[kc], st[1], 0, 0, 0);
    }
    __builtin_amdgcn_s_setprio(0);

    if (kt >= 2 * qt) {
      int kvb = kt * 64;
#pragma unroll
      for (int kvh = 0; kvh < 2; kvh++)
#pragma unroll
        for (int r = 0; r < 16; r++) {
          int kv = kvb + kvh * 32 + (r & 3) + 8 * (r >> 2) + 4 * hi;
          if (kv > qrow) st[kvh][r] = NEG;
        }
    }

    // fixed-max softmax numerator (log2-domain); masked entries -> p = 0
#pragma unroll
    for (int kvh = 0; kvh < 2; kvh++)
#pragma unroll
      for (int r = 0; r < 16; r++) st[kvh][r] = exp2f(st[kvh][r]);

    // P -> bf16 PV A-fragments in-register: per ks, 4 cvt_pk + 2 permlane
    bf16x8 pa[4];
#pragma unroll
    for (int ks = 0; ks < 4; ks++) {
      const f32x16& pp = st[ks >> 1];
      const int s8 = (ks & 1) * 8;
      uint32_t x0 = cvtpk(pp[s8 + 0], pp[s8 + 1]);
      uint32_t x1 = cvtpk(pp[s8 + 2], pp[s8 + 3]);
      uint32_t y0 = cvtpk(pp[s8 + 4], pp[s8 + 5]);
      uint32_t y1 = cvtpk(pp[s8 + 6], pp[s8 + 7]);
      pl32swap(x0, y0);
      pl32swap(x1, y1);
      uint32_t wds[4] = {x0, x1, y0, y1};
      pa[ks] = *reinterpret_cast<const bf16x8*>(wds);
    }

    __builtin_amdgcn_s_setprio(1);
    // row-sum on the matrix pipe: rs_acc += P . ones (all C cols equal)
#pragma unroll
    for (int ks = 0; ks < 4; ks++)
      rs_acc = __builtin_amdgcn_mfma_f32_32x32x16_bf16(pa[ks], onesb, rs_acc, 0, 0, 0);
#pragma unroll
    for (int dh = 0; dh < 2; dh++)
#pragma unroll
      for (int ks = 0; ks < 4; ks++) {
        bf16x8 vb = *reinterpret_cast<const bf16x8*>(
            &Vs[cur][dh * 32 + l31][((2 * ks + hi) ^ swz) * 8]);
        accO[dh] = __builtin_amdgcn_mfma_f32_32x32x16_bf16(pa[ks], vb, accO[dh], 0, 0, 0);
      }
    __builtin_amdgcn_s_setprio(0);
    __syncthreads();
  }

  // ---- epilogue: rs_acc[r] is the row-sum for accO[.][r]'s q-row ----
#pragma unroll
  for (int r = 0; r < 16; r++) {
    float inv = 1.f / rs_acc[r];
    int ql = (r & 3) + 8 * (r >> 2) + 4 * hi;
    int prow = qt * 128 + w * 32 + ql;
    size_t base = ((size_t)(b * 2048 + prow)) * 1024 + h * 64;
    A[base + l31] = f2bf(accO[0][r] * inv);
    A[base + 32 + l31] = f2bf(accO[1][r] * inv);
  }
}

extern "C" void kernel_launch(void* const* d_in, const int* in_sizes, int n_in,
                              void* d_out, int out_size, void* d_ws, size_t ws_size,
                              hipStream_t stream) {
  const float* X  = (const float*)d_in[0];  // residual_stream [2][2048][1024]
  const float* Wq = (const float*)d_in[1];  // weight_query [16][1024][64]
  const float* Wk = (const float*)d_in[2];  // weight_key   [16][1024][64]
  const float* Wv = (const float*)d_in[3];  // weight_value [16][1024][64]
  const float* Wo = (const float*)d_in[4];  // weight_out   [1024][1024]
  float* out = (float*)d_out;               // [2][2048][1024] f32

  u16* ws = (u16*)d_ws;
  u16* WqT = ws;                    // [16][64][1024] x3 contiguous
  u16* WoT = WqT + 3145728;         // [1024][1024]
  u16* Xb  = WoT + 1048576;         // [4096][1024] bf16 (dead after qkv)
  u16* Qb  = Xb + 4194304;          // [32][2048][64]
  u16* Kb  = Qb + 4194304;          // [32][2048][64]
  u16* VT2 = Kb + 4194304;          // [32][32][64][64] tile-blocked
  u16* Ab  = Xb;                    // aliases Xb; total 40 MB

  prep_k<<<dim3(3072), 256, 0, stream>>>(X, Wq, Wk, Wv, Wo, Xb, WqT, WoT);
  qkv_gemm128_k<<<dim3(32, 24), 256, 0, stream>>>(Xb, WqT, Qb, Kb, VT2);
  attn_k<<<dim3(16, 16, 2), 256, 0, stream>>>(Qb, Kb, VT2, Ab);
  out_gemm128_k<<<dim3(32, 8), 256, 0, stream>>>(Ab, WoT, out);
}